// Round 6
// baseline (165.808 us; speedup 1.0000x reference)
//
#include <hip/hip_runtime.h>

#define HID 20
#define BLK 256

typedef float v2f __attribute__((ext_vector_type(2)));
typedef float v4f __attribute__((ext_vector_type(4)));

// Packed SiLU on two activations: pk_mul, 2x v_exp_f32, pk_add, 2x v_rcp_f32,
// pk_mul. Saturates correctly at both ends.
__device__ __forceinline__ v2f silu2(v2f a) {
    v2f m = a * (-1.442695040888963f);
    float e0 = __builtin_amdgcn_exp2f(m.x);
    float e1 = __builtin_amdgcn_exp2f(m.y);
    v2f d = {1.0f + e0, 1.0f + e1};
    v2f r = {__builtin_amdgcn_rcpf(d.x), __builtin_amdgcn_rcpf(d.y)};
    return a * r;
}

// ---- LDS layout (float offsets). All W blocks 16B-aligned; rows are 80B
// apart so every 16B-chunk of a row is 16B-aligned -> clean ds_read_b128.
#define O_W0 0
#define O_B0 20
#define O_W7 40
#define O_B7 60
#define O_W1 64                       // W1..W6: 400 floats each
#define O_WL(l) (O_W1 + ((l) - 1) * 400)
#define O_B1 2464                     // b1..b6: 20 floats each
#define O_BL(l) (O_B1 + ((l) - 1) * 20)
#define SW_TOT 2584

// 20->20 layer on TWO points, K-packed. Weights come from LDS as broadcast
// ds_read_b128 (same addr all lanes -> no conflicts, no SGPR-capacity limit
// that serialized R4/R5's s_load streaming). 4 independent acc chains
// (2 rows x 2 points) of depth 10 -> saturates the FMA pipe at 4-cyc latency.
__device__ __forceinline__ void layer20(const float* __restrict__ sW,
                                        const float* __restrict__ sb,
                                        const v2f (&h)[2][10], v2f (&hn)[2][10]) {
    #pragma unroll
    for (int jp = 0; jp < 10; ++jp) {
        const float* r0 = sW + 40 * jp;   // row 2*jp
        const float* r1 = r0 + 20;        // row 2*jp+1
        v4f w0 = *(const v4f*)(r0);
        v4f w1 = *(const v4f*)(r1);
        v2f w0a = {w0.x, w0.y}, w0b = {w0.z, w0.w};
        v2f w1a = {w1.x, w1.y}, w1b = {w1.z, w1.w};
        v2f a00 = h[0][0] * w0a, a10 = h[1][0] * w0a;   // row0, pt0/pt1
        v2f a01 = h[0][0] * w1a, a11 = h[1][0] * w1a;   // row1, pt0/pt1
        a00 = __builtin_elementwise_fma(h[0][1], w0b, a00);
        a10 = __builtin_elementwise_fma(h[1][1], w0b, a10);
        a01 = __builtin_elementwise_fma(h[0][1], w1b, a01);
        a11 = __builtin_elementwise_fma(h[1][1], w1b, a11);
        #pragma unroll
        for (int q = 1; q < 5; ++q) {
            v4f u0 = *(const v4f*)(r0 + 4 * q);
            v4f u1 = *(const v4f*)(r1 + 4 * q);
            v2f u0a = {u0.x, u0.y}, u0b = {u0.z, u0.w};
            v2f u1a = {u1.x, u1.y}, u1b = {u1.z, u1.w};
            a00 = __builtin_elementwise_fma(h[0][2*q],     u0a, a00);
            a10 = __builtin_elementwise_fma(h[1][2*q],     u0a, a10);
            a01 = __builtin_elementwise_fma(h[0][2*q],     u1a, a01);
            a11 = __builtin_elementwise_fma(h[1][2*q],     u1a, a11);
            a00 = __builtin_elementwise_fma(h[0][2*q + 1], u0b, a00);
            a10 = __builtin_elementwise_fma(h[1][2*q + 1], u0b, a10);
            a01 = __builtin_elementwise_fma(h[0][2*q + 1], u1b, a01);
            a11 = __builtin_elementwise_fma(h[1][2*q + 1], u1b, a11);
        }
        v2f bb = *(const v2f*)(sb + 2 * jp);
        v2f s0 = { a00.x + a00.y + bb.x, a01.x + a01.y + bb.y };  // pt0: rows j,j+1
        v2f s1 = { a10.x + a10.y + bb.x, a11.x + a11.y + bb.y };  // pt1
        hn[0][jp] = silu2(s0);
        hn[1][jp] = silu2(s1);
    }
}

// (256,4): 128-VGPR budget. Live set ~ h[2][10]+hn[2][10] (80) + 4 accs (8)
// + weight temps (16) + misc ~ 115.
__global__ __launch_bounds__(BLK, 4) void SpringEquationNN_70102456205450_kernel(
    const float* __restrict__ t,
    const float* __restrict__ W0, const float* __restrict__ b0,
    const float* __restrict__ W1, const float* __restrict__ b1,
    const float* __restrict__ W2, const float* __restrict__ b2,
    const float* __restrict__ W3, const float* __restrict__ b3,
    const float* __restrict__ W4, const float* __restrict__ b4,
    const float* __restrict__ W5, const float* __restrict__ b5,
    const float* __restrict__ W6, const float* __restrict__ b6,
    const float* __restrict__ W7, const float* __restrict__ b7,
    float* __restrict__ out, int n)
{
    __shared__ float sw[SW_TOT];
    const int tid = threadIdx.x;

    #define STAGE(p, off, m) { for (int k = tid; k < (m); k += BLK) sw[(off) + k] = (p)[k]; }
    STAGE(W0, O_W0, 20)  STAGE(b0, O_B0, 20)
    STAGE(W7, O_W7, 20)  STAGE(b7, O_B7, 1)
    STAGE(W1, O_WL(1), 400) STAGE(W2, O_WL(2), 400) STAGE(W3, O_WL(3), 400)
    STAGE(W4, O_WL(4), 400) STAGE(W5, O_WL(5), 400) STAGE(W6, O_WL(6), 400)
    STAGE(b1, O_BL(1), 20) STAGE(b2, O_BL(2), 20) STAGE(b3, O_BL(3), 20)
    STAGE(b4, O_BL(4), 20) STAGE(b5, O_BL(5), 20) STAGE(b6, O_BL(6), 20)
    #undef STAGE
    __syncthreads();

    const int gid = blockIdx.x * BLK + tid;
    const int p0 = 2 * gid;
    if (p0 >= n) return;

    v2f x = *(const v2f*)(t + p0);   // two consecutive points, 8B coalesced

    v2f h[2][10], hn[2][10];

    // Layer 0: 1 -> 20 for both points
    #pragma unroll
    for (int jp = 0; jp < 10; ++jp) {
        v2f w  = *(const v2f*)(&sw[O_W0 + 2 * jp]);
        v2f bb = *(const v2f*)(&sw[O_B0 + 2 * jp]);
        h[0][jp] = silu2(__builtin_elementwise_fma((v2f){x.x, x.x}, w, bb));
        h[1][jp] = silu2(__builtin_elementwise_fma((v2f){x.y, x.y}, w, bb));
    }

    // Layers 1..6: 20 -> 20, SiLU. Ping-pong h/hn.
    layer20(&sw[O_WL(1)], &sw[O_BL(1)], h, hn);
    layer20(&sw[O_WL(2)], &sw[O_BL(2)], hn, h);
    layer20(&sw[O_WL(3)], &sw[O_BL(3)], h, hn);
    layer20(&sw[O_WL(4)], &sw[O_BL(4)], hn, h);
    layer20(&sw[O_WL(5)], &sw[O_BL(5)], h, hn);
    layer20(&sw[O_WL(6)], &sw[O_BL(6)], hn, h);

    // Layer 7: 20 -> 1, no activation
    v2f w7p  = *(const v2f*)(&sw[O_W7]);
    v2f acc0 = h[0][0] * w7p;
    v2f acc1 = h[1][0] * w7p;
    #pragma unroll
    for (int ip = 1; ip < 10; ++ip) {
        v2f w = *(const v2f*)(&sw[O_W7 + 2 * ip]);
        acc0 = __builtin_elementwise_fma(h[0][ip], w, acc0);
        acc1 = __builtin_elementwise_fma(h[1][ip], w, acc1);
    }
    float bb7 = sw[O_B7];
    v2f o = { acc0.x + acc0.y + bb7, acc1.x + acc1.y + bb7 };
    *(v2f*)(out + p0) = o;   // 8B coalesced
}

extern "C" void kernel_launch(void* const* d_in, const int* in_sizes, int n_in,
                              void* d_out, int out_size, void* d_ws, size_t ws_size,
                              hipStream_t stream) {
    const float* t  = (const float*)d_in[0];
    const float* W0 = (const float*)d_in[1];
    const float* b0 = (const float*)d_in[2];
    const float* W1 = (const float*)d_in[3];
    const float* b1 = (const float*)d_in[4];
    const float* W2 = (const float*)d_in[5];
    const float* b2 = (const float*)d_in[6];
    const float* W3 = (const float*)d_in[7];
    const float* b3 = (const float*)d_in[8];
    const float* W4 = (const float*)d_in[9];
    const float* b4 = (const float*)d_in[10];
    const float* W5 = (const float*)d_in[11];
    const float* b5 = (const float*)d_in[12];
    const float* W6 = (const float*)d_in[13];
    const float* b6 = (const float*)d_in[14];
    const float* W7 = (const float*)d_in[15];
    const float* b7 = (const float*)d_in[16];
    float* out = (float*)d_out;

    int n = in_sizes[0];          // N points
    int threads = (n + 1) / 2;    // 2 points per thread
    int grid = (threads + BLK - 1) / BLK;
    SpringEquationNN_70102456205450_kernel<<<grid, BLK, 0, stream>>>(
        t, W0, b0, W1, b1, W2, b2, W3, b3, W4, b4, W5, b5, W6, b6, W7, b7,
        out, n);
}